// Round 7
// baseline (305.414 us; speedup 1.0000x reference)
//
#include <hip/hip_runtime.h>
#include <math.h>

// Problem constants (fixed by the reference)
constexpr int Bb  = 2;
constexpr int Ss  = 2048;
constexpr int Dd  = 2048;
constexpr int Hh  = 16;
constexpr int DHd = 128;
constexpr int BS  = Bb * Ss;   // 4096
constexpr int NQKV = 2304;     // 2048 q + 128 k + 128 v

typedef __bf16 bf16x8 __attribute__((ext_vector_type(8)));
typedef float  f32x4  __attribute__((ext_vector_type(4)));

// fp32 -> bf16 (RNE), bit-level
static __device__ __forceinline__ unsigned short f2bf(float f) {
  union { float f; unsigned int u; } a; a.f = f;
  unsigned int u = a.u;
  unsigned int r = (u + 0x7fffu + ((u >> 16) & 1u)) >> 16;
  return (unsigned short)r;
}
static __device__ __forceinline__ float bf2f(unsigned short u) {
  union { unsigned int u; float f; } a; a.u = ((unsigned int)u) << 16;
  return a.f;
}
// pack two fp32 -> one dword of 2 bf16 (lo = first), HW RNE pack
static __device__ __forceinline__ int cvtpk(float lo, float hi) {
  int r;
  asm("v_cvt_pk_bf16_f32 %0, %1, %2" : "=v"(r) : "v"(lo), "v"(hi));
  return r;
}
static __device__ __forceinline__ f32x4 mfma16(bf16x8 a, bf16x8 b, f32x4 c) {
  return __builtin_amdgcn_mfma_f32_16x16x32_bf16(a, b, c, 0, 0, 0);
}

// ---------------------------------------------------------------------------
// cast_all: blocks [0,16896): fp32 inputs -> bf16 into one contiguous region
//   [qw (2048x2048) | kvw (256x2048) | ow (2048x2048) | x (4096x2048)]
// blocks [16896,17408): fill RoPE cos/sin table ctab[s][i], s<2048, i<64.
// ---------------------------------------------------------------------------
__global__ __launch_bounds__(256) void cast_all(
    const float* __restrict__ qw, const float* __restrict__ kvw,
    const float* __restrict__ ow, const float* __restrict__ x,
    unsigned short* __restrict__ dst,
    float2* __restrict__ ctab)
{
  const int blk = blockIdx.x;
  if (blk >= 16896) {                              // RoPE table fill
    const int id = (blk - 16896) * 256 + threadIdx.x;  // 0..131071
    const int s = id >> 6, i = id & 63;
    const float invf = exp2f(-(float)i * (13.287712379549449f / 64.0f));
    const float ang = (float)s * invf;
    ctab[id] = make_float2(cosf(ang), sinf(ang));
    return;
  }
  const int i = blk * 256 + threadIdx.x;
  const float* src; int off;
  if (i < 1048576)      { src = qw;  off = 0; }
  else if (i < 1179648) { src = kvw; off = 1048576; }
  else if (i < 2228224) { src = ow;  off = 1179648; }
  else                  { src = x;   off = 2228224; }
  const float4 v = ((const float4*)src)[i - off];
  ushort4 o;
  o.x = f2bf(v.x); o.y = f2bf(v.y); o.z = f2bf(v.z); o.w = f2bf(v.w);
  ((ushort4*)dst)[i] = o;
}

// ---------------------------------------------------------------------------
// bf16 MFMA GEMM: C[M][N] = A[M][K] @ Bw[N][K]^T + bias(col).
// bias(col) = col < nsplit ? bias1[col] : bias2[col-nsplit]  (merged QKV).
// 128x128 tile, BK=32, 256 threads, global_load_lds width-16 staging.
// ---------------------------------------------------------------------------
#define TM 128
#define TN 128
#define TK 32

#define GLOAD16(gp, lp)                                                        \
  __builtin_amdgcn_global_load_lds(                                            \
      (const __attribute__((address_space(1))) void*)(gp),                     \
      (__attribute__((address_space(3))) void*)(lp), 16, 0, 0)

template <bool BF16OUT>
__global__ __launch_bounds__(256) void gemm_bt_mfma(
    const unsigned short* __restrict__ A,    // M x K bf16
    const unsigned short* __restrict__ Bw,   // N x K bf16
    const float* __restrict__ bias1,
    const float* __restrict__ bias2,
    int nsplit,
    void* __restrict__ Cv,                   // M x N (fp32 or bf16)
    int M, int N, int K)
{
  __shared__ unsigned short As[TM * TK];   // 8 KB
  __shared__ unsigned short Bs[TN * TK];   // 8 KB

  const int tid  = threadIdx.x;
  const int w    = tid >> 6;
  const int lane = tid & 63;
  const int m0   = blockIdx.y * TM;
  const int n0   = blockIdx.x * TN;
  const int wm   = (w >> 1) * 64;
  const int wn   = (w & 1) * 64;

  f32x4 acc[4][4];
#pragma unroll
  for (int i = 0; i < 4; i++)
#pragma unroll
    for (int j = 0; j < 4; j++) acc[i][j] = (f32x4){0.f, 0.f, 0.f, 0.f};

  const int srow = lane >> 2;
  const int scol = (lane & 3) * 8;
  const unsigned short* aG0 = A  + (size_t)(m0 +      w * 16 + srow) * K + scol;
  const unsigned short* aG1 = A  + (size_t)(m0 + 64 + w * 16 + srow) * K + scol;
  const unsigned short* bG0 = Bw + (size_t)(n0 +      w * 16 + srow) * K + scol;
  const unsigned short* bG1 = Bw + (size_t)(n0 + 64 + w * 16 + srow) * K + scol;
  unsigned short* aL0 = &As[(     w * 16) * TK];
  unsigned short* aL1 = &As[(64 + w * 16) * TK];
  unsigned short* bL0 = &Bs[(     w * 16) * TK];
  unsigned short* bL1 = &Bs[(64 + w * 16) * TK];

  const int fr = lane & 15;
  const int fk = (lane >> 4) * 8;

  for (int k0 = 0; k0 < K; k0 += TK) {
    __syncthreads();
    GLOAD16(aG0 + k0, aL0);
    GLOAD16(aG1 + k0, aL1);
    GLOAD16(bG0 + k0, bL0);
    GLOAD16(bG1 + k0, bL1);
    __syncthreads();

    bf16x8 af[4], bfr[4];
#pragma unroll
    for (int i = 0; i < 4; i++)
      af[i] = *(const bf16x8*)&As[(wm + i * 16 + fr) * TK + fk];
#pragma unroll
    for (int j = 0; j < 4; j++)
      bfr[j] = *(const bf16x8*)&Bs[(wn + j * 16 + fr) * TK + fk];
#pragma unroll
    for (int i = 0; i < 4; i++)
#pragma unroll
      for (int j = 0; j < 4; j++)
        acc[i][j] = mfma16(af[i], bfr[j], acc[i][j]);
  }

  const int er = (lane >> 4) * 4;
  const int ec = lane & 15;
#pragma unroll
  for (int j = 0; j < 4; j++) {
    const int col = n0 + wn + j * 16 + ec;
    const float bv = (col < nsplit) ? bias1[col] : bias2[col - nsplit];
#pragma unroll
    for (int i = 0; i < 4; i++) {
      const int rbase = m0 + wm + i * 16 + er;
#pragma unroll
      for (int r = 0; r < 4; r++) {
        const float v = acc[i][j][r] + bv;
        if constexpr (BF16OUT)
          ((unsigned short*)Cv)[(size_t)(rbase + r) * N + col] = f2bf(v);
        else
          ((float*)Cv)[(size_t)(rbase + r) * N + col] = v;
      }
    }
  }
}

// ---------------------------------------------------------------------------
// prep_kv: from QKV bf16 (B,S,2304) — k cols [2048,2176), v cols [2176,2304) —
// produce Kb (B,S,128) roped (table-driven) and Vt (B,128,S) transposed.
// ---------------------------------------------------------------------------
__global__ __launch_bounds__(256) void prep_kv(
    const unsigned short* __restrict__ QKV,
    const float2* __restrict__ ctab,
    unsigned short* __restrict__ Kb,
    unsigned short* __restrict__ Vt)
{
  __shared__ unsigned short Vtile[64 * 136];   // [s_local][d], padded

  const int blk = blockIdx.x;          // b*32 + stile
  const int b   = blk >> 5;
  const int s0  = (blk & 31) * 64;
  const int t   = threadIdx.x;

  // --- rope K (cos/sin from table)
  {
    const int r = t >> 2, p = t & 3;
    const int row = blk * 64 + r;
    const int s = row & (Ss - 1);
    const unsigned short* src = QKV + (size_t)row * NQKV + 2048 + p * 16;
    const float2* ct = ctab + s * 64 + p * 16;
    union { uint4 v[2]; unsigned short a[16]; } lo, hi, ol, oh;
    lo.v[0] = *(const uint4*)src;        lo.v[1] = *(const uint4*)(src + 8);
    hi.v[0] = *(const uint4*)(src + 64); hi.v[1] = *(const uint4*)(src + 72);
#pragma unroll
    for (int e = 0; e < 16; e++) {
      const float2 cs = ct[e];
      const float l = bf2f(lo.a[e]), hh = bf2f(hi.a[e]);
      ol.a[e] = f2bf(l * cs.x - hh * cs.y);
      oh.a[e] = f2bf(hh * cs.x + l * cs.y);
    }
    unsigned short* dst = Kb + (size_t)row * 128 + p * 16;
    *(uint4*)dst        = ol.v[0]; *(uint4*)(dst + 8)  = ol.v[1];
    *(uint4*)(dst + 64) = oh.v[0]; *(uint4*)(dst + 72) = oh.v[1];
  }

  // --- stage V into LDS, s-major
#pragma unroll
  for (int c = 0; c < 4; c++) {
    const int id = c * 256 + t;
    const int vr = id >> 4, cc = id & 15;
    *(uint4*)&Vtile[vr * 136 + cc * 8] =
        *(const uint4*)(QKV + (size_t)(blk * 64 + vr) * NQKV + 2176 + cc * 8);
  }
  __syncthreads();

  // --- write Vt rows
  {
    const int d = t >> 1, half = t & 1;
    union { uint4 v[4]; unsigned short a[32]; } val;
#pragma unroll
    for (int kk = 0; kk < 32; kk++)
      val.a[kk] = Vtile[(half * 32 + kk) * 136 + d];
    unsigned short* dst = Vt + ((size_t)(b * 128 + d)) * Ss + s0 + half * 32;
#pragma unroll
    for (int c = 0; c < 4; c++) *(uint4*)(dst + c * 8) = val.v[c];
  }
}

// ---------------------------------------------------------------------------
// flash_v12: v11 (paired q-tiles, VALU diet) restructured for latency:
//  - 64-key tiles, DOUBLE-BUFFERED LDS (2x16K K + 2x16K V = 64 KB; residency
//    stays 2 blocks/CU -> iso-occupancy, unlike R0's failed dbuf). T3 2-phase:
//    stage(next) issued right after the barrier, one barrier per tile, loads
//    land under the compute phase.
//  - tile64_2: both 32-key halves interleaved -> 4 independent depth-4 QK
//    chains + 2 independent softmax streams per wave (2x ILP in the
//    latency-dominated regions).
// ---------------------------------------------------------------------------
__global__ __launch_bounds__(256, 2) void flash_v12(
    const unsigned short* __restrict__ QKV,  // (B,S,2304), q RAW (rope here)
    const unsigned short* __restrict__ Kb,   // (B,S,128) roped
    const unsigned short* __restrict__ Vt,   // (B,128,S)
    const float2* __restrict__ ctab,         // (2048, 64) cos/sin
    unsigned short* __restrict__ attn)       // (B,S,2048) bf16
{
  __shared__ unsigned short Ks[2 * 8192];  // buf: 4 panels [64 key][32 dh], 16KB
  __shared__ unsigned short Vs[2 * 8192];  // buf: 2 panels [128 dh][32 key], 16KB

  // --- decode: co-resident {c, c+256} -> complementary p
  const int g  = (int)blockIdx.x;          // 0..511
  const int lo = g & 255, hi = g >> 8;
  const int p  = hi ? (15 - (lo & 15)) : (lo & 15);
  const int hb = (lo >> 4) + 16 * hi;      // 0..31
  const int h  = hb & 15;
  const int b  = hb >> 4;

  const int qA0 = (31 - p) * 64;           // heavy tile base (>= 1024)
  const int qB0 = p * 64;                  // light tile base (< 1024)

  const int tid = threadIdx.x;
  const int w = tid >> 6, lane = tid & 63;
  const int lg = lane >> 4, lm = lane & 15;
  const int qrowA = qA0 + w * 16 + lm;
  const int qrowA_lo = qA0 + w * 16;
  const int qrowA_hi = qA0 + w * 16 + 15;
  const int qrowB = qB0 + w * 16 + lm;
  const int qrowB_lo = qB0 + w * 16;
  const int qrowB_hi = qB0 + w * 16 + 15;

  // swizzled frag slot: row contributions >=16 vanish mod 4 -> lane-constant
  const int klg = lg ^ ((lm >> 1) & 3);

  const float sscale = 0.08838834764831845f * 1.4426950408889634f; // /sqrt(128)*log2e

  // --- Q frags with fused table RoPE, PRE-SCALED by sscale (both tiles)
  bf16x8 qfA[4], qfB[4];
  {
    union U8 { bf16x8 v; unsigned short a[8]; };
#pragma unroll
    for (int tile = 0; tile < 2; tile++) {
      const int qrow = tile ? qrowB : qrowA;
      const unsigned short* qp =
          QKV + (size_t)(b * Ss + qrow) * NQKV + h * DHd + lg * 8;
      const float2* ct = ctab + qrow * 64 + lg * 8;
      U8 lo0, lo1, hi0, hi1, ol0, ol1, oh0, oh1;
      lo0.v = *(const bf16x8*)(qp);
      lo1.v = *(const bf16x8*)(qp + 32);
      hi0.v = *(const bf16x8*)(qp + 64);
      hi1.v = *(const bf16x8*)(qp + 96);
#pragma unroll
      for (int j = 0; j < 8; j++) {
        {
          const float2 cs = ct[j];                      // i = lg*8+j
          const float l = bf2f(lo0.a[j]), hh = bf2f(hi0.a[j]);
          ol0.a[j] = f2bf((l * cs.x - hh * cs.y) * sscale);
          oh0.a[j] = f2bf((hh * cs.x + l * cs.y) * sscale);
        }
        {
          const float2 cs = ct[32 + j];                 // i = 32+lg*8+j
          const float l = bf2f(lo1.a[j]), hh = bf2f(hi1.a[j]);
          ol1.a[j] = f2bf((l * cs.x - hh * cs.y) * sscale);
          oh1.a[j] = f2bf((hh * cs.x + l * cs.y) * sscale);
        }
      }
      if (tile == 0) { qfA[0]=ol0.v; qfA[1]=ol1.v; qfA[2]=oh0.v; qfA[3]=oh1.v; }
      else           { qfB[0]=ol0.v; qfB[1]=ol1.v; qfB[2]=oh0.v; qfB[3]=oh1.v; }
    }
  }

  // O^T accumulators, C-layout: (dh = dt*16 + 4*lg + r, qrow = lm)
  f32x4 otA[8], otB[8];
#pragma unroll
  for (int dt = 0; dt < 8; dt++) {
    otA[dt] = (f32x4){0.f, 0.f, 0.f, 0.f};
    otB[dt] = (f32x4){0.f, 0.f, 0.f, 0.f};
  }
  float lsumA = 0.f, lsumB = 0.f;

  // staging lane addresses; global chunk permuted so linear LDS dest holds
  // the slot-swizzled layout: chunk(lane) = (lane&3) ^ ((lane>>3)&3)
  const int sr  = lane >> 2;                             // row-within-16
  const int sc8 = ((lane & 3) ^ ((lane >> 3) & 3)) * 8;  // swizzled 16B chunk
  const unsigned short* kg =
      Kb + (size_t)b * Ss * 128 + (size_t)sr * 128 + w * 32 + sc8;
  const unsigned short* vg =
      Vt + (size_t)b * 128 * Ss + (size_t)(w * 32 + sr) * Ss + sc8;

  // issue the 8 global_load_lds for 64-key tile at jj into buffer bi
  auto stage = [&](int bi, int jj) {
    unsigned short* ksl  = &Ks[bi * 8192 + w * 2048];
    unsigned short* vsl0 = &Vs[bi * 8192 + (w * 32) * 32];
    unsigned short* vsl1 = &Vs[bi * 8192 + 4096 + (w * 32) * 32];
#pragma unroll
    for (int i = 0; i < 4; i++)
      GLOAD16(kg + (size_t)(jj + i * 16) * 128, ksl + i * 512);
#pragma unroll
    for (int i = 0; i < 2; i++) {
      GLOAD16(vg + (size_t)(i * 16) * Ss + jj,      vsl0 + i * 512);
      GLOAD16(vg + (size_t)(i * 16) * Ss + jj + 32, vsl1 + i * 512);
    }
  };

  // transpose shuffle sources (C->B layout, within a 32-key half)
  const int addr0 = (2 * (lg & 1)) * 16 + lm;   // dwords 0,1
  const int addr1 = addr0 + 16;                 // dwords 2,3
  const bool sel_hi = (lg & 2) != 0;

  // single 32-key half (keys jj..jj+31 = buffer rows 0..31)
  auto half32 = [&](const unsigned short* KsB, const unsigned short* VsB,
                    int keybase, const bf16x8 (&qf)[4], f32x4 (&ot)[8],
                    float& lsum, int qrow, int qrow_lo) {
    f32x4 s[2];
    s[0] = (f32x4){0.f, 0.f, 0.f, 0.f};
    s[1] = (f32x4){0.f, 0.f, 0.f, 0.f};
    __builtin_amdgcn_s_setprio(1);
#pragma unroll
    for (int kf = 0; kf < 4; kf++) {
      const bf16x8 k0 = *(const bf16x8*)&KsB[kf * 2048 + (      lm) * 32 + klg * 8];
      const bf16x8 k1 = *(const bf16x8*)&KsB[kf * 2048 + (16 + lm) * 32 + klg * 8];
      s[0] = mfma16(k0, qf[kf], s[0]);
      s[1] = mfma16(k1, qf[kf], s[1]);
    }
    __builtin_amdgcn_s_setprio(0);
    const bool needmask = keybase + 31 > qrow_lo;
    int pk[2][2];
#pragma unroll
    for (int t = 0; t < 2; t++) {
      float pv[4];
#pragma unroll
      for (int r = 0; r < 4; r++) pv[r] = exp2f(s[t][r]);
      if (needmask) {
        const int kb = keybase + t * 16 + 4 * lg;
#pragma unroll
        for (int r = 0; r < 4; r++)
          if (kb + r > qrow) pv[r] = 0.f;
      }
#pragma unroll
      for (int r = 0; r < 4; r++) lsum += pv[r];
      pk[t][0] = cvtpk(pv[0], pv[1]);
      pk[t][1] = cvtpk(pv[2], pv[3]);
    }
    union { int d[4]; bf16x8 v; } pb;
#pragma unroll
    for (int d = 0; d < 4; d++) {
      const int src = (d < 2) ? addr0 : addr1;
      const int v0 = __shfl(pk[0][d & 1], src);
      const int v1 = __shfl(pk[1][d & 1], src);
      pb.d[d] = sel_hi ? v1 : v0;
    }
    __builtin_amdgcn_s_setprio(1);
#pragma unroll
    for (int dt = 0; dt < 8; dt++) {
      const bf16x8 vf = *(const bf16x8*)&VsB[(dt * 16 + lm) * 32 + klg * 8];
      ot[dt] = mfma16(vf, pb.v, ot[dt]);
    }
    __builtin_amdgcn_s_setprio(0);
  };

  // both 32-key halves of a 64-key tile, stages interleaved (2x ILP)
  auto tile64_2 = [&](const unsigned short* KsB, const unsigned short* VsB,
                      int keybase, const bf16x8 (&qf)[4], f32x4 (&ot)[8],
                      float& lsum, int qrow, int qrow_lo) {
    f32x4 s[2][2];
#pragma unroll
    for (int hf = 0; hf < 2; hf++) {
      s[hf][0] = (f32x4){0.f, 0.f, 0.f, 0.f};
      s[hf][1] = (f32x4){0.f, 0.f, 0.f, 0.f};
    }
    __builtin_amdgcn_s_setprio(1);
#pragma unroll
    for (int kf = 0; kf < 4; kf++) {
      const bf16x8 k00 = *(const bf16x8*)&KsB[kf * 2048 + (      lm) * 32 + klg * 8];
      const bf16x8 k01 = *(const bf16x8*)&KsB[kf * 2048 + (16 + lm) * 32 + klg * 8];
      const bf16x8 k10 = *(const bf16x8*)&KsB[kf * 2048 + (32 + lm) * 32 + klg * 8];
      const bf16x8 k11 = *(const bf16x8*)&KsB[kf * 2048 + (48 + lm) * 32 + klg * 8];
      s[0][0] = mfma16(k00, qf[kf], s[0][0]);
      s[0][1] = mfma16(k01, qf[kf], s[0][1]);
      s[1][0] = mfma16(k10, qf[kf], s[1][0]);
      s[1][1] = mfma16(k11, qf[kf], s[1][1]);
    }
    __builtin_amdgcn_s_setprio(0);
    int pk[2][2][2];
#pragma unroll
    for (int hf = 0; hf < 2; hf++) {
      const bool needmask = keybase + hf * 32 + 31 > qrow_lo;
#pragma unroll
      for (int t = 0; t < 2; t++) {
        float pv[4];
#pragma unroll
        for (int r = 0; r < 4; r++) pv[r] = exp2f(s[hf][t][r]);
        if (needmask) {
          const int kb = keybase + hf * 32 + t * 16 + 4 * lg;
#pragma unroll
          for (int r = 0; r < 4; r++)
            if (kb + r > qrow) pv[r] = 0.f;
        }
#pragma unroll
        for (int r = 0; r < 4; r++) lsum += pv[r];
        pk[hf][t][0] = cvtpk(pv[0], pv[1]);
        pk[hf][t][1] = cvtpk(pv[2], pv[3]);
      }
    }
    union { int d[4]; bf16x8 v; } pb[2];
#pragma unroll
    for (int hf = 0; hf < 2; hf++) {
#pragma unroll
      for (int d = 0; d < 4; d++) {
        const int src = (d < 2) ? addr0 : addr1;
        const int v0 = __shfl(pk[hf][0][d & 1], src);
        const int v1 = __shfl(pk[hf][1][d & 1], src);
        pb[hf].d[d] = sel_hi ? v1 : v0;
      }
    }
    __builtin_amdgcn_s_setprio(1);
#pragma unroll
    for (int dt = 0; dt < 8; dt++) {
      const bf16x8 vf0 = *(const bf16x8*)&VsB[       (dt * 16 + lm) * 32 + klg * 8];
      const bf16x8 vf1 = *(const bf16x8*)&VsB[4096 + (dt * 16 + lm) * 32 + klg * 8];
      ot[dt] = mfma16(vf0, pb[0].v, ot[dt]);
      ot[dt] = mfma16(vf1, pb[1].v, ot[dt]);
    }
    __builtin_amdgcn_s_setprio(0);
  };

  // --- main loop: 2-phase double-buffered
  stage(0, 0);
  int cur = 0;
  for (int j0 = 0; j0 <= qA0; j0 += 64) {
    __syncthreads();            // drains buf[cur]'s staging; readers of
                                // buf[cur^1] (prev iter) all done
    if (j0 + 64 <= qA0) stage(cur ^ 1, j0 + 64);

    const unsigned short* KsB = &Ks[cur * 8192];
    const unsigned short* VsB = &Vs[cur * 8192];

    // tile A (heavy): half0 always active (j0 <= qA0 <= qrowA_hi)
    if (j0 + 32 <= qrowA_hi)
      tile64_2(KsB, VsB, j0, qfA, otA, lsumA, qrowA, qrowA_lo);
    else
      half32(KsB, VsB, j0, qfA, otA, lsumA, qrowA, qrowA_lo);

    // tile B (light): same staged K/V (MQA)
    if (j0 <= qrowB_hi) {
      if (j0 + 32 <= qrowB_hi)
        tile64_2(KsB, VsB, j0, qfB, otB, lsumB, qrowB, qrowB_lo);
      else
        half32(KsB, VsB, j0, qfB, otB, lsumB, qrowB, qrowB_lo);
    }
    cur ^= 1;
  }

  // --- epilogue x2: reduce lsum over the 4 lg groups, normalize, store
#pragma unroll
  for (int tile = 0; tile < 2; tile++) {
    float lsum = tile ? lsumB : lsumA;
    const int qrow = tile ? qrowB : qrowA;
    lsum += __shfl_xor(lsum, 16);
    lsum += __shfl_xor(lsum, 32);
    const float inv = 1.0f / lsum;
    unsigned short* dst =
        attn + (size_t)(b * Ss + qrow) * Dd + h * DHd + lg * 4;
#pragma unroll
    for (int dt = 0; dt < 8; dt++) {
      const f32x4 o = tile ? otB[dt] : otA[dt];
      uint2 st;
      st.x = (unsigned int)cvtpk(o[0] * inv, o[1] * inv);
      st.y = (unsigned int)cvtpk(o[2] * inv, o[3] * inv);
      *(uint2*)(dst + dt * 16) = st;
    }
  }
}

// ---------------------------------------------------------------------------
extern "C" void kernel_launch(void* const* d_in, const int* in_sizes, int n_in,
                              void* d_out, int out_size, void* d_ws, size_t ws_size,
                              hipStream_t stream) {
  const float* x   = (const float*)d_in[0];   // (B,S,D)
  const float* qw  = (const float*)d_in[1];   // (2048, 2048)
  const float* qb  = (const float*)d_in[2];
  const float* kvw = (const float*)d_in[3];   // (256, 2048)
  const float* kvb = (const float*)d_in[4];
  const float* ow  = (const float*)d_in[5];   // (2048, 2048)
  const float* ob  = (const float*)d_in[6];
  float* out = (float*)d_out;

  // workspace layout (bf16 elements):
  //   wqkv @ 0          (2304 x 2048)   qw rows 0-2047, kvw 2048-2303
  //   owb  @ 4,718,592  (2048 x 2048)
  //   xb   @ 8,912,896  (4096 x 2048)   -> reused as attn_b
  //   QKV  @ 17,301,504 (4096 x 2304)
  //   Kb   @ 26,738,688 (4096 x 128)
  //   Vt   @ 27,262,976 (2 x 128 x 2048)
  //   ctab @ 27,787,264 (2048 x 64 float2 = 1 MB)
  unsigned short* wsb    = (unsigned short*)d_ws;
  unsigned short* wqkv   = wsb;
  unsigned short* owb    = wsb + 4718592;
  unsigned short* xb     = wsb + 8912896;
  unsigned short* attn_b = xb;                 // alias: xb dead after QKV gemm
  unsigned short* QKV    = wsb + 17301504;
  unsigned short* Kb     = wsb + 26738688;
  unsigned short* Vt     = wsb + 27262976;
  float2*         ctab   = (float2*)(wsb + 27787264);

  // 1. all fp32->bf16 casts + RoPE cos/sin table in one kernel
  cast_all<<<17408, 256, 0, stream>>>(qw, kvw, ow, x, wqkv, ctab);

  // 2. merged QKV projection: (4096 x 2304) = xb @ wqkv^T + [qb|kvb]
  gemm_bt_mfma<true><<<dim3(NQKV / TN, BS / TM), 256, 0, stream>>>(
      xb, wqkv, qb, kvb, 2048, QKV, BS, NQKV, Dd);

  // 3. K rope (table) + V transpose (Q rope fused into flash_v12)
  prep_kv<<<BS / 64, 256, 0, stream>>>(QKV, ctab, Kb, Vt);

  // 4. flash attention (paired q-tiles, 64-key double-buffered 2-phase)
  flash_v12<<<512, 256, 0, stream>>>(QKV, Kb, Vt, ctab, attn_b);

  // 5. O projection: out = attn @ ow^T + ob (fp32 out)
  gemm_bt_mfma<false><<<dim3(Dd / TN, BS / TM), 256, 0, stream>>>(
      attn_b, owb, ob, ob, Dd, out, BS, Dd, Dd);
}

// Round 8
// 304.673 us; speedup vs baseline: 1.0024x; 1.0024x over previous
//
#include <hip/hip_runtime.h>
#include <math.h>

// Problem constants (fixed by the reference)
constexpr int Bb  = 2;
constexpr int Ss  = 2048;
constexpr int Dd  = 2048;
constexpr int Hh  = 16;
constexpr int DHd = 128;
constexpr int BS  = Bb * Ss;   // 4096
constexpr int NQKV = 2304;     // 2048 q + 128 k + 128 v

typedef __bf16 bf16x8 __attribute__((ext_vector_type(8)));
typedef float  f32x4  __attribute__((ext_vector_type(4)));

// fp32 -> bf16 (RNE), bit-level
static __device__ __forceinline__ unsigned short f2bf(float f) {
  union { float f; unsigned int u; } a; a.f = f;
  unsigned int u = a.u;
  unsigned int r = (u + 0x7fffu + ((u >> 16) & 1u)) >> 16;
  return (unsigned short)r;
}
static __device__ __forceinline__ float bf2f(unsigned short u) {
  union { unsigned int u; float f; } a; a.u = ((unsigned int)u) << 16;
  return a.f;
}
// pack two fp32 -> one dword of 2 bf16 (lo = first), HW RNE pack
static __device__ __forceinline__ int cvtpk(float lo, float hi) {
  int r;
  asm("v_cvt_pk_bf16_f32 %0, %1, %2" : "=v"(r) : "v"(lo), "v"(hi));
  return r;
}
static __device__ __forceinline__ f32x4 mfma16(bf16x8 a, bf16x8 b, f32x4 c) {
  return __builtin_amdgcn_mfma_f32_16x16x32_bf16(a, b, c, 0, 0, 0);
}

// ---------------------------------------------------------------------------
// cast_all: blocks [0,16896): fp32 inputs -> bf16 into one contiguous region
//   [qw (2048x2048) | kvw (256x2048) | ow (2048x2048) | x (4096x2048)]
// blocks [16896,17408): fill RoPE cos/sin table ctab[s][i], s<2048, i<64.
// ---------------------------------------------------------------------------
__global__ __launch_bounds__(256) void cast_all(
    const float* __restrict__ qw, const float* __restrict__ kvw,
    const float* __restrict__ ow, const float* __restrict__ x,
    unsigned short* __restrict__ dst,
    float2* __restrict__ ctab)
{
  const int blk = blockIdx.x;
  if (blk >= 16896) {                              // RoPE table fill
    const int id = (blk - 16896) * 256 + threadIdx.x;  // 0..131071
    const int s = id >> 6, i = id & 63;
    const float invf = exp2f(-(float)i * (13.287712379549449f / 64.0f));
    const float ang = (float)s * invf;
    ctab[id] = make_float2(cosf(ang), sinf(ang));
    return;
  }
  const int i = blk * 256 + threadIdx.x;
  const float* src; int off;
  if (i < 1048576)      { src = qw;  off = 0; }
  else if (i < 1179648) { src = kvw; off = 1048576; }
  else if (i < 2228224) { src = ow;  off = 1179648; }
  else                  { src = x;   off = 2228224; }
  const float4 v = ((const float4*)src)[i - off];
  ushort4 o;
  o.x = f2bf(v.x); o.y = f2bf(v.y); o.z = f2bf(v.z); o.w = f2bf(v.w);
  ((ushort4*)dst)[i] = o;
}

// ---------------------------------------------------------------------------
// bf16 MFMA GEMM: C[M][N] = A[M][K] @ Bw[N][K]^T + bias(col).
// bias(col) = col < nsplit ? bias1[col] : bias2[col-nsplit]  (merged QKV).
// 128x128 tile, BK=32, 256 threads, global_load_lds width-16 staging.
// ---------------------------------------------------------------------------
#define TM 128
#define TN 128
#define TK 32

#define GLOAD16(gp, lp)                                                        \
  __builtin_amdgcn_global_load_lds(                                            \
      (const __attribute__((address_space(1))) void*)(gp),                     \
      (__attribute__((address_space(3))) void*)(lp), 16, 0, 0)

template <bool BF16OUT>
__global__ __launch_bounds__(256) void gemm_bt_mfma(
    const unsigned short* __restrict__ A,    // M x K bf16
    const unsigned short* __restrict__ Bw,   // N x K bf16
    const float* __restrict__ bias1,
    const float* __restrict__ bias2,
    int nsplit,
    void* __restrict__ Cv,                   // M x N (fp32 or bf16)
    int M, int N, int K)
{
  __shared__ unsigned short As[TM * TK];   // 8 KB
  __shared__ unsigned short Bs[TN * TK];   // 8 KB

  const int tid  = threadIdx.x;
  const int w    = tid >> 6;
  const int lane = tid & 63;
  const int m0   = blockIdx.y * TM;
  const int n0   = blockIdx.x * TN;
  const int wm   = (w >> 1) * 64;
  const int wn   = (w & 1) * 64;

  f32x4 acc[4][4];
#pragma unroll
  for (int i = 0; i < 4; i++)
#pragma unroll
    for (int j = 0; j < 4; j++) acc[i][j] = (f32x4){0.f, 0.f, 0.f, 0.f};

  const int srow = lane >> 2;
  const int scol = (lane & 3) * 8;
  const unsigned short* aG0 = A  + (size_t)(m0 +      w * 16 + srow) * K + scol;
  const unsigned short* aG1 = A  + (size_t)(m0 + 64 + w * 16 + srow) * K + scol;
  const unsigned short* bG0 = Bw + (size_t)(n0 +      w * 16 + srow) * K + scol;
  const unsigned short* bG1 = Bw + (size_t)(n0 + 64 + w * 16 + srow) * K + scol;
  unsigned short* aL0 = &As[(     w * 16) * TK];
  unsigned short* aL1 = &As[(64 + w * 16) * TK];
  unsigned short* bL0 = &Bs[(     w * 16) * TK];
  unsigned short* bL1 = &Bs[(64 + w * 16) * TK];

  const int fr = lane & 15;
  const int fk = (lane >> 4) * 8;

  for (int k0 = 0; k0 < K; k0 += TK) {
    __syncthreads();
    GLOAD16(aG0 + k0, aL0);
    GLOAD16(aG1 + k0, aL1);
    GLOAD16(bG0 + k0, bL0);
    GLOAD16(bG1 + k0, bL1);
    __syncthreads();

    bf16x8 af[4], bfr[4];
#pragma unroll
    for (int i = 0; i < 4; i++)
      af[i] = *(const bf16x8*)&As[(wm + i * 16 + fr) * TK + fk];
#pragma unroll
    for (int j = 0; j < 4; j++)
      bfr[j] = *(const bf16x8*)&Bs[(wn + j * 16 + fr) * TK + fk];
#pragma unroll
    for (int i = 0; i < 4; i++)
#pragma unroll
      for (int j = 0; j < 4; j++)
        acc[i][j] = mfma16(af[i], bfr[j], acc[i][j]);
  }

  const int er = (lane >> 4) * 4;
  const int ec = lane & 15;
#pragma unroll
  for (int j = 0; j < 4; j++) {
    const int col = n0 + wn + j * 16 + ec;
    const float bv = (col < nsplit) ? bias1[col] : bias2[col - nsplit];
#pragma unroll
    for (int i = 0; i < 4; i++) {
      const int rbase = m0 + wm + i * 16 + er;
#pragma unroll
      for (int r = 0; r < 4; r++) {
        const float v = acc[i][j][r] + bv;
        if constexpr (BF16OUT)
          ((unsigned short*)Cv)[(size_t)(rbase + r) * N + col] = f2bf(v);
        else
          ((float*)Cv)[(size_t)(rbase + r) * N + col] = v;
      }
    }
  }
}

// ---------------------------------------------------------------------------
// prep_kv: from QKV bf16 (B,S,2304) — k cols [2048,2176), v cols [2176,2304) —
// produce Kb (B,S,128) roped (table-driven) and Vt (B,128,S) transposed.
// ---------------------------------------------------------------------------
__global__ __launch_bounds__(256) void prep_kv(
    const unsigned short* __restrict__ QKV,
    const float2* __restrict__ ctab,
    unsigned short* __restrict__ Kb,
    unsigned short* __restrict__ Vt)
{
  __shared__ unsigned short Vtile[64 * 136];   // [s_local][d], padded

  const int blk = blockIdx.x;          // b*32 + stile
  const int b   = blk >> 5;
  const int s0  = (blk & 31) * 64;
  const int t   = threadIdx.x;

  // --- rope K (cos/sin from table)
  {
    const int r = t >> 2, p = t & 3;
    const int row = blk * 64 + r;
    const int s = row & (Ss - 1);
    const unsigned short* src = QKV + (size_t)row * NQKV + 2048 + p * 16;
    const float2* ct = ctab + s * 64 + p * 16;
    union { uint4 v[2]; unsigned short a[16]; } lo, hi, ol, oh;
    lo.v[0] = *(const uint4*)src;        lo.v[1] = *(const uint4*)(src + 8);
    hi.v[0] = *(const uint4*)(src + 64); hi.v[1] = *(const uint4*)(src + 72);
#pragma unroll
    for (int e = 0; e < 16; e++) {
      const float2 cs = ct[e];
      const float l = bf2f(lo.a[e]), hh = bf2f(hi.a[e]);
      ol.a[e] = f2bf(l * cs.x - hh * cs.y);
      oh.a[e] = f2bf(hh * cs.x + l * cs.y);
    }
    unsigned short* dst = Kb + (size_t)row * 128 + p * 16;
    *(uint4*)dst        = ol.v[0]; *(uint4*)(dst + 8)  = ol.v[1];
    *(uint4*)(dst + 64) = oh.v[0]; *(uint4*)(dst + 72) = oh.v[1];
  }

  // --- stage V into LDS, s-major
#pragma unroll
  for (int c = 0; c < 4; c++) {
    const int id = c * 256 + t;
    const int vr = id >> 4, cc = id & 15;
    *(uint4*)&Vtile[vr * 136 + cc * 8] =
        *(const uint4*)(QKV + (size_t)(blk * 64 + vr) * NQKV + 2176 + cc * 8);
  }
  __syncthreads();

  // --- write Vt rows
  {
    const int d = t >> 1, half = t & 1;
    union { uint4 v[4]; unsigned short a[32]; } val;
#pragma unroll
    for (int kk = 0; kk < 32; kk++)
      val.a[kk] = Vtile[(half * 32 + kk) * 136 + d];
    unsigned short* dst = Vt + ((size_t)(b * 128 + d)) * Ss + s0 + half * 32;
#pragma unroll
    for (int c = 0; c < 4; c++) *(uint4*)(dst + c * 8) = val.v[c];
  }
}

// ---------------------------------------------------------------------------
// flash_v13: v11 body (paired q-tiles, 128-key single-buffer, slot-XOR LDS,
// table Q-rope, VALU diet) at 512 THREADS / 8 WAVES per block.
// v11/v12 were latency-bound at 2 waves/SIMD (issue-work floor ~12 us vs
// 79-87 us measured; both dbuf attempts failed). The pair block has exactly
// 8 16-row q-subtiles (4 of heavy tile A + 4 of light tile B): wave w<4 ->
// A-subtile w, wave w>=4 -> B-subtile w-4. Staging: waves 0-3 -> K panels,
// waves 4-7 -> V panels (identical LDS image to v11). LDS stays 64 KB ->
// 2 blocks/CU -> 16 waves/CU = 4 waves/SIMD (2x TLP); per-wave VGPR drops
// (one ot[8]/qf[4] instead of two).
// ---------------------------------------------------------------------------
__global__ __launch_bounds__(512, 4) void flash_v13(
    const unsigned short* __restrict__ QKV,  // (B,S,2304), q RAW (rope here)
    const unsigned short* __restrict__ Kb,   // (B,S,128) roped
    const unsigned short* __restrict__ Vt,   // (B,128,S)
    const float2* __restrict__ ctab,         // (2048, 64) cos/sin
    unsigned short* __restrict__ attn)       // (B,S,2048) bf16
{
  __shared__ unsigned short Ks[4 * 128 * 32];  // panel kf: [key128][dh32], 32 KB
  __shared__ unsigned short Vs[4 * 128 * 32];  // panel ks2: [dh128][key32], 32 KB

  // --- decode: co-resident {c, c+256} -> complementary p
  const int g  = (int)blockIdx.x;          // 0..511
  const int lo = g & 255, hi = g >> 8;
  const int p  = hi ? (15 - (lo & 15)) : (lo & 15);
  const int hb = (lo >> 4) + 16 * hi;      // 0..31
  const int h  = hb & 15;
  const int b  = hb >> 4;

  const int qA0 = (31 - p) * 64;           // heavy tile base (>= 1024)
  const int qB0 = p * 64;                  // light tile base (< 1024)

  const int tid = threadIdx.x;
  const int w = tid >> 6, lane = tid & 63;
  const int lg = lane >> 4, lm = lane & 15;

  // wave role: w<4 -> tile A subtile w; w>=4 -> tile B subtile w-4
  const bool isA = (w < 4);
  const int sw = w & 3;
  const int qt0 = isA ? qA0 : qB0;
  const int qrow    = qt0 + sw * 16 + lm;
  const int qrow_lo = qt0 + sw * 16;
  const int qrow_hi = qt0 + sw * 16 + 15;

  // swizzled frag slot: row contributions >=16 vanish mod 4 -> lane-constant
  const int klg = lg ^ ((lm >> 1) & 3);

  const float sscale = 0.08838834764831845f * 1.4426950408889634f; // /sqrt(128)*log2e

  // --- Q frag with fused table RoPE, PRE-SCALED by sscale
  bf16x8 qf[4];
  {
    union U8 { bf16x8 v; unsigned short a[8]; };
    const unsigned short* qp =
        QKV + (size_t)(b * Ss + qrow) * NQKV + h * DHd + lg * 8;
    const float2* ct = ctab + qrow * 64 + lg * 8;
    U8 lo0, lo1, hi0, hi1, ol0, ol1, oh0, oh1;
    lo0.v = *(const bf16x8*)(qp);
    lo1.v = *(const bf16x8*)(qp + 32);
    hi0.v = *(const bf16x8*)(qp + 64);
    hi1.v = *(const bf16x8*)(qp + 96);
#pragma unroll
    for (int j = 0; j < 8; j++) {
      {
        const float2 cs = ct[j];                      // i = lg*8+j
        const float l = bf2f(lo0.a[j]), hh = bf2f(hi0.a[j]);
        ol0.a[j] = f2bf((l * cs.x - hh * cs.y) * sscale);
        oh0.a[j] = f2bf((hh * cs.x + l * cs.y) * sscale);
      }
      {
        const float2 cs = ct[32 + j];                 // i = 32+lg*8+j
        const float l = bf2f(lo1.a[j]), hh = bf2f(hi1.a[j]);
        ol1.a[j] = f2bf((l * cs.x - hh * cs.y) * sscale);
        oh1.a[j] = f2bf((hh * cs.x + l * cs.y) * sscale);
      }
    }
    qf[0] = ol0.v; qf[1] = ol1.v; qf[2] = oh0.v; qf[3] = oh1.v;
  }

  // O^T accumulator, C-layout: (dh = dt*16 + 4*lg + r, qrow = lm)
  f32x4 ot[8];
#pragma unroll
  for (int dt = 0; dt < 8; dt++) ot[dt] = (f32x4){0.f, 0.f, 0.f, 0.f};
  float lsum = 0.f;

  // staging lane addresses; global chunk permuted so linear LDS dest holds
  // the slot-swizzled layout: chunk(lane) = (lane&3) ^ ((lane>>3)&3)
  const int sr  = lane >> 2;                             // row-within-16
  const int sc8 = ((lane & 3) ^ ((lane >> 3) & 3)) * 8;  // swizzled 16B chunk
  // K stager (waves 0-3): panel w = dh w*32..+31, 128 keys (8 GLOADs)
  const unsigned short* kg =
      Kb + (size_t)b * Ss * 128 + (size_t)sr * 128 + (w & 3) * 32 + sc8;
  unsigned short* ksl = &Ks[(w & 3) * 4096];
  // V stager (waves 4-7): panel ks2 = w-4 (keys ks2*32..+31), dh 0..127
  const int vks = w & 3;
  const unsigned short* vg =
      Vt + (size_t)b * 128 * Ss + (size_t)sr * Ss + sc8;
  unsigned short* vsl = &Vs[vks * 4096];

  // transpose shuffle sources (C->B layout, within a 32-key half)
  const int addr0 = (2 * (lg & 1)) * 16 + lm;   // dwords 0,1
  const int addr1 = addr0 + 16;                 // dwords 2,3
  const bool sel_hi = (lg & 2) != 0;

  // one 32-key half: S^T tiles tA,tA+1 -> exp -> transpose -> PV on panel VsP
  auto half32 = [&](int keybase, int tA, const unsigned short* VsP,
                    bool needmask) {
    f32x4 s[2];
    s[0] = (f32x4){0.f, 0.f, 0.f, 0.f};
    s[1] = (f32x4){0.f, 0.f, 0.f, 0.f};
    __builtin_amdgcn_s_setprio(1);
#pragma unroll
    for (int kf = 0; kf < 4; kf++) {
      const bf16x8 k0 = *(const bf16x8*)&Ks[kf * 4096 + ((tA)     * 16 + lm) * 32 + klg * 8];
      const bf16x8 k1 = *(const bf16x8*)&Ks[kf * 4096 + ((tA + 1) * 16 + lm) * 32 + klg * 8];
      s[0] = mfma16(k0, qf[kf], s[0]);
      s[1] = mfma16(k1, qf[kf], s[1]);
    }
    __builtin_amdgcn_s_setprio(0);
    // exp2 (max-free, Q pre-scaled) + diagonal-only mask + pack
    int pk[2][2];
#pragma unroll
    for (int t = 0; t < 2; t++) {
      float pv[4];
#pragma unroll
      for (int r = 0; r < 4; r++) pv[r] = exp2f(s[t][r]);
      if (needmask) {
        const int kb = keybase + t * 16 + 4 * lg;
#pragma unroll
        for (int r = 0; r < 4; r++)
          if (kb + r > qrow) pv[r] = 0.f;
      }
#pragma unroll
      for (int r = 0; r < 4; r++) lsum += pv[r];
      pk[t][0] = cvtpk(pv[0], pv[1]);
      pk[t][1] = cvtpk(pv[2], pv[3]);
    }
    // C-layout -> B-layout transpose (8 bpermutes)
    union { int d[4]; bf16x8 v; } pb;
#pragma unroll
    for (int d = 0; d < 4; d++) {
      const int src = (d < 2) ? addr0 : addr1;
      const int v0 = __shfl(pk[0][d & 1], src);
      const int v1 = __shfl(pk[1][d & 1], src);
      pb.d[d] = sel_hi ? v1 : v0;
    }
    // O^T += V^T(32 keys) · P^T
    __builtin_amdgcn_s_setprio(1);
#pragma unroll
    for (int dt = 0; dt < 8; dt++) {
      const bf16x8 vfrag = *(const bf16x8*)&VsP[(dt * 16 + lm) * 32 + klg * 8];
      ot[dt] = mfma16(vfrag, pb.v, ot[dt]);
    }
    __builtin_amdgcn_s_setprio(0);
  };

  for (int j0 = 0; j0 <= qA0; j0 += 128) {
    __syncthreads();            // previous iteration's LDS readers done
    if (isA) {
      // stage K panel (w&3): keys j0..j0+127, dh (w&3)*32..+31
#pragma unroll
      for (int i = 0; i < 8; i++)
        GLOAD16(kg + (size_t)(j0 + i * 16) * 128, ksl + i * 512);
    } else {
      // stage V panel vks: dh 0..127, keys j0+vks*32..+31
#pragma unroll
      for (int i = 0; i < 8; i++)
        GLOAD16(vg + (size_t)(i * 16) * Ss + j0 + vks * 32, vsl + i * 512);
    }
    __syncthreads();            // vmcnt(0) drained before use

    // my subtile: process active 32-key halves
#pragma unroll
    for (int t32 = 0; t32 < 4; t32++) {
      const int kb = j0 + t32 * 32;
      if (kb <= qrow_hi)                      // wave-uniform
        half32(kb, t32 * 2, &Vs[t32 * 4096], kb + 31 > qrow_lo);
    }
  }

  // --- epilogue: reduce lsum over the 4 lg groups, normalize, store
  lsum += __shfl_xor(lsum, 16);
  lsum += __shfl_xor(lsum, 32);
  const float inv = 1.0f / lsum;
  unsigned short* dst =
      attn + (size_t)(b * Ss + qrow) * Dd + h * DHd + lg * 4;
#pragma unroll
  for (int dt = 0; dt < 8; dt++) {
    uint2 st;
    st.x = (unsigned int)cvtpk(ot[dt][0] * inv, ot[dt][1] * inv);
    st.y = (unsigned int)cvtpk(ot[dt][2] * inv, ot[dt][3] * inv);
    *(uint2*)(dst + dt * 16) = st;
  }
}

// ---------------------------------------------------------------------------
extern "C" void kernel_launch(void* const* d_in, const int* in_sizes, int n_in,
                              void* d_out, int out_size, void* d_ws, size_t ws_size,
                              hipStream_t stream) {
  const float* x   = (const float*)d_in[0];   // (B,S,D)
  const float* qw  = (const float*)d_in[1];   // (2048, 2048)
  const float* qb  = (const float*)d_in[2];
  const float* kvw = (const float*)d_in[3];   // (256, 2048)
  const float* kvb = (const float*)d_in[4];
  const float* ow  = (const float*)d_in[5];   // (2048, 2048)
  const float* ob  = (const float*)d_in[6];
  float* out = (float*)d_out;

  // workspace layout (bf16 elements):
  //   wqkv @ 0          (2304 x 2048)   qw rows 0-2047, kvw 2048-2303
  //   owb  @ 4,718,592  (2048 x 2048)
  //   xb   @ 8,912,896  (4096 x 2048)   -> reused as attn_b
  //   QKV  @ 17,301,504 (4096 x 2304)
  //   Kb   @ 26,738,688 (4096 x 128)
  //   Vt   @ 27,262,976 (2 x 128 x 2048)
  //   ctab @ 27,787,264 (2048 x 64 float2 = 1 MB)
  unsigned short* wsb    = (unsigned short*)d_ws;
  unsigned short* wqkv   = wsb;
  unsigned short* owb    = wsb + 4718592;
  unsigned short* xb     = wsb + 8912896;
  unsigned short* attn_b = xb;                 // alias: xb dead after QKV gemm
  unsigned short* QKV    = wsb + 17301504;
  unsigned short* Kb     = wsb + 26738688;
  unsigned short* Vt     = wsb + 27262976;
  float2*         ctab   = (float2*)(wsb + 27787264);

  // 1. all fp32->bf16 casts + RoPE cos/sin table in one kernel
  cast_all<<<17408, 256, 0, stream>>>(qw, kvw, ow, x, wqkv, ctab);

  // 2. merged QKV projection: (4096 x 2304) = xb @ wqkv^T + [qb|kvb]
  gemm_bt_mfma<true><<<dim3(NQKV / TN, BS / TM), 256, 0, stream>>>(
      xb, wqkv, qb, kvb, 2048, QKV, BS, NQKV, Dd);

  // 3. K rope (table) + V transpose (Q rope fused into flash_v13)
  prep_kv<<<BS / 64, 256, 0, stream>>>(QKV, ctab, Kb, Vt);

  // 4. flash attention (8-wave pair blocks: 4 waves/SIMD)
  flash_v13<<<512, 512, 0, stream>>>(QKV, Kb, Vt, ctab, attn_b);

  // 5. O projection: out = attn @ ow^T + ob (fp32 out)
  gemm_bt_mfma<false><<<dim3(Dd / TN, BS / TM), 256, 0, stream>>>(
      attn_b, owb, ob, ob, Dd, out, BS, Dd, Dd);
}

// Round 9
// 302.932 us; speedup vs baseline: 1.0082x; 1.0057x over previous
//
#include <hip/hip_runtime.h>
#include <math.h>

// Problem constants (fixed by the reference)
constexpr int Bb  = 2;
constexpr int Ss  = 2048;
constexpr int Dd  = 2048;
constexpr int Hh  = 16;
constexpr int DHd = 128;
constexpr int BS  = Bb * Ss;   // 4096
constexpr int NQKV = 2304;     // 2048 q + 128 k + 128 v

typedef __bf16 bf16x8 __attribute__((ext_vector_type(8)));
typedef float  f32x4  __attribute__((ext_vector_type(4)));

// fp32 -> bf16 (RNE), bit-level
static __device__ __forceinline__ unsigned short f2bf(float f) {
  union { float f; unsigned int u; } a; a.f = f;
  unsigned int u = a.u;
  unsigned int r = (u + 0x7fffu + ((u >> 16) & 1u)) >> 16;
  return (unsigned short)r;
}
static __device__ __forceinline__ float bf2f(unsigned short u) {
  union { unsigned int u; float f; } a; a.u = ((unsigned int)u) << 16;
  return a.f;
}
// pack two fp32 -> one dword of 2 bf16 (lo = first), HW RNE pack
static __device__ __forceinline__ int cvtpk(float lo, float hi) {
  int r;
  asm("v_cvt_pk_bf16_f32 %0, %1, %2" : "=v"(r) : "v"(lo), "v"(hi));
  return r;
}
static __device__ __forceinline__ f32x4 mfma16(bf16x8 a, bf16x8 b, f32x4 c) {
  return __builtin_amdgcn_mfma_f32_16x16x32_bf16(a, b, c, 0, 0, 0);
}

// ---------------------------------------------------------------------------
// cast_all: blocks [0,2048): GRID-STRIDE fp32->bf16 casts (G11: tiny-block
// dispatch overhead) over 4,325,376 float4 items:
//   [qw (2048x2048) | kvw (256x2048) | ow (2048x2048) | x (4096x2048)]
// blocks [2048,2560): fill RoPE cos/sin table ctab[s][i], s<2048, i<64.
// ---------------------------------------------------------------------------
constexpr int CAST_ITEMS = 4325376;   // total float4 elements
constexpr int CAST_BLOCKS = 2048;

__global__ __launch_bounds__(256) void cast_all(
    const float* __restrict__ qw, const float* __restrict__ kvw,
    const float* __restrict__ ow, const float* __restrict__ x,
    unsigned short* __restrict__ dst,
    float2* __restrict__ ctab)
{
  const int blk = blockIdx.x;
  if (blk >= CAST_BLOCKS) {                        // RoPE table fill
    const int id = (blk - CAST_BLOCKS) * 256 + threadIdx.x;  // 0..131071
    const int s = id >> 6, i = id & 63;
    const float invf = exp2f(-(float)i * (13.287712379549449f / 64.0f));
    const float ang = (float)s * invf;
    ctab[id] = make_float2(cosf(ang), sinf(ang));
    return;
  }
  for (int i = blk * 256 + threadIdx.x; i < CAST_ITEMS; i += CAST_BLOCKS * 256) {
    const float* src; int off;
    if (i < 1048576)      { src = qw;  off = 0; }
    else if (i < 1179648) { src = kvw; off = 1048576; }
    else if (i < 2228224) { src = ow;  off = 1179648; }
    else                  { src = x;   off = 2228224; }
    const float4 v = ((const float4*)src)[i - off];
    ushort4 o;
    o.x = f2bf(v.x); o.y = f2bf(v.y); o.z = f2bf(v.z); o.w = f2bf(v.w);
    ((ushort4*)dst)[i] = o;
  }
}

// ---------------------------------------------------------------------------
// bf16 MFMA GEMM: C[M][N] = A[M][K] @ Bw[N][K]^T + bias(col).
// bias(col) = col < nsplit ? bias1[col] : bias2[col-nsplit]  (merged QKV).
// 128x128 tile, BK=32, 256 threads, global_load_lds width-16 staging.
// ---------------------------------------------------------------------------
#define TM 128
#define TN 128
#define TK 32

#define GLOAD16(gp, lp)                                                        \
  __builtin_amdgcn_global_load_lds(                                            \
      (const __attribute__((address_space(1))) void*)(gp),                     \
      (__attribute__((address_space(3))) void*)(lp), 16, 0, 0)

template <bool BF16OUT>
__global__ __launch_bounds__(256) void gemm_bt_mfma(
    const unsigned short* __restrict__ A,    // M x K bf16
    const unsigned short* __restrict__ Bw,   // N x K bf16
    const float* __restrict__ bias1,
    const float* __restrict__ bias2,
    int nsplit,
    void* __restrict__ Cv,                   // M x N (fp32 or bf16)
    int M, int N, int K)
{
  __shared__ unsigned short As[TM * TK];   // 8 KB
  __shared__ unsigned short Bs[TN * TK];   // 8 KB

  const int tid  = threadIdx.x;
  const int w    = tid >> 6;
  const int lane = tid & 63;
  const int m0   = blockIdx.y * TM;
  const int n0   = blockIdx.x * TN;
  const int wm   = (w >> 1) * 64;
  const int wn   = (w & 1) * 64;

  f32x4 acc[4][4];
#pragma unroll
  for (int i = 0; i < 4; i++)
#pragma unroll
    for (int j = 0; j < 4; j++) acc[i][j] = (f32x4){0.f, 0.f, 0.f, 0.f};

  const int srow = lane >> 2;
  const int scol = (lane & 3) * 8;
  const unsigned short* aG0 = A  + (size_t)(m0 +      w * 16 + srow) * K + scol;
  const unsigned short* aG1 = A  + (size_t)(m0 + 64 + w * 16 + srow) * K + scol;
  const unsigned short* bG0 = Bw + (size_t)(n0 +      w * 16 + srow) * K + scol;
  const unsigned short* bG1 = Bw + (size_t)(n0 + 64 + w * 16 + srow) * K + scol;
  unsigned short* aL0 = &As[(     w * 16) * TK];
  unsigned short* aL1 = &As[(64 + w * 16) * TK];
  unsigned short* bL0 = &Bs[(     w * 16) * TK];
  unsigned short* bL1 = &Bs[(64 + w * 16) * TK];

  const int fr = lane & 15;
  const int fk = (lane >> 4) * 8;

  for (int k0 = 0; k0 < K; k0 += TK) {
    __syncthreads();
    GLOAD16(aG0 + k0, aL0);
    GLOAD16(aG1 + k0, aL1);
    GLOAD16(bG0 + k0, bL0);
    GLOAD16(bG1 + k0, bL1);
    __syncthreads();

    bf16x8 af[4], bfr[4];
#pragma unroll
    for (int i = 0; i < 4; i++)
      af[i] = *(const bf16x8*)&As[(wm + i * 16 + fr) * TK + fk];
#pragma unroll
    for (int j = 0; j < 4; j++)
      bfr[j] = *(const bf16x8*)&Bs[(wn + j * 16 + fr) * TK + fk];
#pragma unroll
    for (int i = 0; i < 4; i++)
#pragma unroll
      for (int j = 0; j < 4; j++)
        acc[i][j] = mfma16(af[i], bfr[j], acc[i][j]);
  }

  const int er = (lane >> 4) * 4;
  const int ec = lane & 15;
#pragma unroll
  for (int j = 0; j < 4; j++) {
    const int col = n0 + wn + j * 16 + ec;
    const float bv = (col < nsplit) ? bias1[col] : bias2[col - nsplit];
#pragma unroll
    for (int i = 0; i < 4; i++) {
      const int rbase = m0 + wm + i * 16 + er;
#pragma unroll
      for (int r = 0; r < 4; r++) {
        const float v = acc[i][j][r] + bv;
        if constexpr (BF16OUT)
          ((unsigned short*)Cv)[(size_t)(rbase + r) * N + col] = f2bf(v);
        else
          ((float*)Cv)[(size_t)(rbase + r) * N + col] = v;
      }
    }
  }
}

// ---------------------------------------------------------------------------
// prep_kv: from QKV bf16 (B,S,2304) — k cols [2048,2176), v cols [2176,2304) —
// produce Kb (B,S,128) roped (table-driven) and Vt (B,128,S) transposed.
// 128 blocks x 32 s-rows (was 64 x 64: only 64/256 CUs busy).
// ---------------------------------------------------------------------------
__global__ __launch_bounds__(256) void prep_kv(
    const unsigned short* __restrict__ QKV,
    const float2* __restrict__ ctab,
    unsigned short* __restrict__ Kb,
    unsigned short* __restrict__ Vt)
{
  __shared__ unsigned short Vtile[32 * 136];   // [s_local][d], padded

  const int blk = blockIdx.x;          // b*64 + stile
  const int b   = blk >> 6;
  const int s0  = (blk & 63) * 32;
  const int t   = threadIdx.x;

  // --- rope K (cos/sin from table): 8 threads/row, 8 elems each
  {
    const int r = t >> 3, p = t & 7;
    const int row = blk * 32 + r;
    const int s = row & (Ss - 1);
    const unsigned short* src = QKV + (size_t)row * NQKV + 2048 + p * 8;
    const float2* ct = ctab + s * 64 + p * 8;
    union { uint4 v; unsigned short a[8]; } lo, hi, ol, oh;
    lo.v = *(const uint4*)src;
    hi.v = *(const uint4*)(src + 64);
#pragma unroll
    for (int e = 0; e < 8; e++) {
      const float2 cs = ct[e];
      const float l = bf2f(lo.a[e]), hh = bf2f(hi.a[e]);
      ol.a[e] = f2bf(l * cs.x - hh * cs.y);
      oh.a[e] = f2bf(hh * cs.x + l * cs.y);
    }
    unsigned short* dst = Kb + (size_t)row * 128 + p * 8;
    *(uint4*)dst        = ol.v;
    *(uint4*)(dst + 64) = oh.v;
  }

  // --- stage V into LDS, s-major (32 rows x 128 cols)
#pragma unroll
  for (int c = 0; c < 2; c++) {
    const int id = c * 256 + t;
    const int vr = id >> 4, cc = id & 15;
    *(uint4*)&Vtile[vr * 136 + cc * 8] =
        *(const uint4*)(QKV + (size_t)(blk * 32 + vr) * NQKV + 2176 + cc * 8);
  }
  __syncthreads();

  // --- write Vt rows: d = t>>1 (128 dhs), half = t&1, 16 keys each
  {
    const int d = t >> 1, half = t & 1;
    union { uint4 v[2]; unsigned short a[16]; } val;
#pragma unroll
    for (int kk = 0; kk < 16; kk++)
      val.a[kk] = Vtile[(half * 16 + kk) * 136 + d];
    unsigned short* dst = Vt + ((size_t)(b * 128 + d)) * Ss + s0 + half * 16;
    *(uint4*)dst       = val.v[0];
    *(uint4*)(dst + 8) = val.v[1];
  }
}

// ---------------------------------------------------------------------------
// flash_v13 (unchanged from R7, proven 74.3 us): paired q-tiles, 128-key
// single-buffer, slot-XOR LDS, table Q-rope, VALU diet, 512 threads / 8 waves
// (wave w<4 -> A-subtile w, w>=4 -> B-subtile w-4; K/V staging split by role).
// ---------------------------------------------------------------------------
__global__ __launch_bounds__(512, 4) void flash_v13(
    const unsigned short* __restrict__ QKV,  // (B,S,2304), q RAW (rope here)
    const unsigned short* __restrict__ Kb,   // (B,S,128) roped
    const unsigned short* __restrict__ Vt,   // (B,128,S)
    const float2* __restrict__ ctab,         // (2048, 64) cos/sin
    unsigned short* __restrict__ attn)       // (B,S,2048) bf16
{
  __shared__ unsigned short Ks[4 * 128 * 32];  // panel kf: [key128][dh32], 32 KB
  __shared__ unsigned short Vs[4 * 128 * 32];  // panel ks2: [dh128][key32], 32 KB

  // --- decode: co-resident {c, c+256} -> complementary p
  const int g  = (int)blockIdx.x;          // 0..511
  const int lo = g & 255, hi = g >> 8;
  const int p  = hi ? (15 - (lo & 15)) : (lo & 15);
  const int hb = (lo >> 4) + 16 * hi;      // 0..31
  const int h  = hb & 15;
  const int b  = hb >> 4;

  const int qA0 = (31 - p) * 64;           // heavy tile base (>= 1024)
  const int qB0 = p * 64;                  // light tile base (< 1024)

  const int tid = threadIdx.x;
  const int w = tid >> 6, lane = tid & 63;
  const int lg = lane >> 4, lm = lane & 15;

  // wave role: w<4 -> tile A subtile w; w>=4 -> tile B subtile w-4
  const bool isA = (w < 4);
  const int sw = w & 3;
  const int qt0 = isA ? qA0 : qB0;
  const int qrow    = qt0 + sw * 16 + lm;
  const int qrow_lo = qt0 + sw * 16;
  const int qrow_hi = qt0 + sw * 16 + 15;

  // swizzled frag slot: row contributions >=16 vanish mod 4 -> lane-constant
  const int klg = lg ^ ((lm >> 1) & 3);

  const float sscale = 0.08838834764831845f * 1.4426950408889634f; // /sqrt(128)*log2e

  // --- Q frag with fused table RoPE, PRE-SCALED by sscale
  bf16x8 qf[4];
  {
    union U8 { bf16x8 v; unsigned short a[8]; };
    const unsigned short* qp =
        QKV + (size_t)(b * Ss + qrow) * NQKV + h * DHd + lg * 8;
    const float2* ct = ctab + qrow * 64 + lg * 8;
    U8 lo0, lo1, hi0, hi1, ol0, ol1, oh0, oh1;
    lo0.v = *(const bf16x8*)(qp);
    lo1.v = *(const bf16x8*)(qp + 32);
    hi0.v = *(const bf16x8*)(qp + 64);
    hi1.v = *(const bf16x8*)(qp + 96);
#pragma unroll
    for (int j = 0; j < 8; j++) {
      {
        const float2 cs = ct[j];                      // i = lg*8+j
        const float l = bf2f(lo0.a[j]), hh = bf2f(hi0.a[j]);
        ol0.a[j] = f2bf((l * cs.x - hh * cs.y) * sscale);
        oh0.a[j] = f2bf((hh * cs.x + l * cs.y) * sscale);
      }
      {
        const float2 cs = ct[32 + j];                 // i = 32+lg*8+j
        const float l = bf2f(lo1.a[j]), hh = bf2f(hi1.a[j]);
        ol1.a[j] = f2bf((l * cs.x - hh * cs.y) * sscale);
        oh1.a[j] = f2bf((hh * cs.x + l * cs.y) * sscale);
      }
    }
    qf[0] = ol0.v; qf[1] = ol1.v; qf[2] = oh0.v; qf[3] = oh1.v;
  }

  // O^T accumulator, C-layout: (dh = dt*16 + 4*lg + r, qrow = lm)
  f32x4 ot[8];
#pragma unroll
  for (int dt = 0; dt < 8; dt++) ot[dt] = (f32x4){0.f, 0.f, 0.f, 0.f};
  float lsum = 0.f;

  // staging lane addresses; global chunk permuted so linear LDS dest holds
  // the slot-swizzled layout: chunk(lane) = (lane&3) ^ ((lane>>3)&3)
  const int sr  = lane >> 2;                             // row-within-16
  const int sc8 = ((lane & 3) ^ ((lane >> 3) & 3)) * 8;  // swizzled 16B chunk
  // K stager (waves 0-3): panel w = dh w*32..+31, 128 keys (8 GLOADs)
  const unsigned short* kg =
      Kb + (size_t)b * Ss * 128 + (size_t)sr * 128 + (w & 3) * 32 + sc8;
  unsigned short* ksl = &Ks[(w & 3) * 4096];
  // V stager (waves 4-7): panel ks2 = w-4 (keys ks2*32..+31), dh 0..127
  const int vks = w & 3;
  const unsigned short* vg =
      Vt + (size_t)b * 128 * Ss + (size_t)sr * Ss + sc8;
  unsigned short* vsl = &Vs[vks * 4096];

  // transpose shuffle sources (C->B layout, within a 32-key half)
  const int addr0 = (2 * (lg & 1)) * 16 + lm;   // dwords 0,1
  const int addr1 = addr0 + 16;                 // dwords 2,3
  const bool sel_hi = (lg & 2) != 0;

  // one 32-key half: S^T tiles tA,tA+1 -> exp -> transpose -> PV on panel VsP
  auto half32 = [&](int keybase, int tA, const unsigned short* VsP,
                    bool needmask) {
    f32x4 s[2];
    s[0] = (f32x4){0.f, 0.f, 0.f, 0.f};
    s[1] = (f32x4){0.f, 0.f, 0.f, 0.f};
    __builtin_amdgcn_s_setprio(1);
#pragma unroll
    for (int kf = 0; kf < 4; kf++) {
      const bf16x8 k0 = *(const bf16x8*)&Ks[kf * 4096 + ((tA)     * 16 + lm) * 32 + klg * 8];
      const bf16x8 k1 = *(const bf16x8*)&Ks[kf * 4096 + ((tA + 1) * 16 + lm) * 32 + klg * 8];
      s[0] = mfma16(k0, qf[kf], s[0]);
      s[1] = mfma16(k1, qf[kf], s[1]);
    }
    __builtin_amdgcn_s_setprio(0);
    // exp2 (max-free, Q pre-scaled) + diagonal-only mask + pack
    int pk[2][2];
#pragma unroll
    for (int t = 0; t < 2; t++) {
      float pv[4];
#pragma unroll
      for (int r = 0; r < 4; r++) pv[r] = exp2f(s[t][r]);
      if (needmask) {
        const int kb = keybase + t * 16 + 4 * lg;
#pragma unroll
        for (int r = 0; r < 4; r++)
          if (kb + r > qrow) pv[r] = 0.f;
      }
#pragma unroll
      for (int r = 0; r < 4; r++) lsum += pv[r];
      pk[t][0] = cvtpk(pv[0], pv[1]);
      pk[t][1] = cvtpk(pv[2], pv[3]);
    }
    // C-layout -> B-layout transpose (8 bpermutes)
    union { int d[4]; bf16x8 v; } pb;
#pragma unroll
    for (int d = 0; d < 4; d++) {
      const int src = (d < 2) ? addr0 : addr1;
      const int v0 = __shfl(pk[0][d & 1], src);
      const int v1 = __shfl(pk[1][d & 1], src);
      pb.d[d] = sel_hi ? v1 : v0;
    }
    // O^T += V^T(32 keys) · P^T
    __builtin_amdgcn_s_setprio(1);
#pragma unroll
    for (int dt = 0; dt < 8; dt++) {
      const bf16x8 vfrag = *(const bf16x8*)&VsP[(dt * 16 + lm) * 32 + klg * 8];
      ot[dt] = mfma16(vfrag, pb.v, ot[dt]);
    }
    __builtin_amdgcn_s_setprio(0);
  };

  for (int j0 = 0; j0 <= qA0; j0 += 128) {
    __syncthreads();            // previous iteration's LDS readers done
    if (isA) {
      // stage K panel (w&3): keys j0..j0+127, dh (w&3)*32..+31
#pragma unroll
      for (int i = 0; i < 8; i++)
        GLOAD16(kg + (size_t)(j0 + i * 16) * 128, ksl + i * 512);
    } else {
      // stage V panel vks: dh 0..127, keys j0+vks*32..+31
#pragma unroll
      for (int i = 0; i < 8; i++)
        GLOAD16(vg + (size_t)(i * 16) * Ss + j0 + vks * 32, vsl + i * 512);
    }
    __syncthreads();            // vmcnt(0) drained before use

    // my subtile: process active 32-key halves
#pragma unroll
    for (int t32 = 0; t32 < 4; t32++) {
      const int kb = j0 + t32 * 32;
      if (kb <= qrow_hi)                      // wave-uniform
        half32(kb, t32 * 2, &Vs[t32 * 4096], kb + 31 > qrow_lo);
    }
  }

  // --- epilogue: reduce lsum over the 4 lg groups, normalize, store
  lsum += __shfl_xor(lsum, 16);
  lsum += __shfl_xor(lsum, 32);
  const float inv = 1.0f / lsum;
  unsigned short* dst =
      attn + (size_t)(b * Ss + qrow) * Dd + h * DHd + lg * 4;
#pragma unroll
  for (int dt = 0; dt < 8; dt++) {
    uint2 st;
    st.x = (unsigned int)cvtpk(ot[dt][0] * inv, ot[dt][1] * inv);
    st.y = (unsigned int)cvtpk(ot[dt][2] * inv, ot[dt][3] * inv);
    *(uint2*)(dst + dt * 16) = st;
  }
}

// ---------------------------------------------------------------------------
extern "C" void kernel_launch(void* const* d_in, const int* in_sizes, int n_in,
                              void* d_out, int out_size, void* d_ws, size_t ws_size,
                              hipStream_t stream) {
  const float* x   = (const float*)d_in[0];   // (B,S,D)
  const float* qw  = (const float*)d_in[1];   // (2048, 2048)
  const float* qb  = (const float*)d_in[2];
  const float* kvw = (const float*)d_in[3];   // (256, 2048)
  const float* kvb = (const float*)d_in[4];
  const float* ow  = (const float*)d_in[5];   // (2048, 2048)
  const float* ob  = (const float*)d_in[6];
  float* out = (float*)d_out;

  // workspace layout (bf16 elements):
  //   wqkv @ 0          (2304 x 2048)   qw rows 0-2047, kvw 2048-2303
  //   owb  @ 4,718,592  (2048 x 2048)
  //   xb   @ 8,912,896  (4096 x 2048)   -> reused as attn_b
  //   QKV  @ 17,301,504 (4096 x 2304)
  //   Kb   @ 26,738,688 (4096 x 128)
  //   Vt   @ 27,262,976 (2 x 128 x 2048)
  //   ctab @ 27,787,264 (2048 x 64 float2 = 1 MB)
  unsigned short* wsb    = (unsigned short*)d_ws;
  unsigned short* wqkv   = wsb;
  unsigned short* owb    = wsb + 4718592;
  unsigned short* xb     = wsb + 8912896;
  unsigned short* attn_b = xb;                 // alias: xb dead after QKV gemm
  unsigned short* QKV    = wsb + 17301504;
  unsigned short* Kb     = wsb + 26738688;
  unsigned short* Vt     = wsb + 27262976;
  float2*         ctab   = (float2*)(wsb + 27787264);

  // 1. all fp32->bf16 casts (grid-stride, 2048 blocks) + RoPE table
  cast_all<<<2560, 256, 0, stream>>>(qw, kvw, ow, x, wqkv, ctab);

  // 2. merged QKV projection: (4096 x 2304) = xb @ wqkv^T + [qb|kvb]
  gemm_bt_mfma<true><<<dim3(NQKV / TN, BS / TM), 256, 0, stream>>>(
      xb, wqkv, qb, kvb, 2048, QKV, BS, NQKV, Dd);

  // 3. K rope (table) + V transpose (128 blocks; Q rope fused into flash)
  prep_kv<<<BS / 32, 256, 0, stream>>>(QKV, ctab, Kb, Vt);

  // 4. flash attention (8-wave pair blocks: 4 waves/SIMD)
  flash_v13<<<512, 512, 0, stream>>>(QKV, Kb, Vt, ctab, attn_b);

  // 5. O projection: out = attn @ ow^T + ob (fp32 out)
  gemm_bt_mfma<false><<<dim3(Dd / TN, BS / TM), 256, 0, stream>>>(
      attn_b, owb, ob, ob, Dd, out, BS, Dd, Dd);
}